// Round 13
// baseline (204.623 us; speedup 1.0000x reference)
//
#include <hip/hip_runtime.h>
#include <cstdint>
#include <cstddef>

// ---------------------------------------------------------------------------
// ChatGPTAttention: x[2,2048,1024] -> QKV proj -> causal MHA (16 heads, dk=64)
//                   -> O proj. bf16 MFMA pipeline, fp32 accumulate.
// Q is pre-scaled by 1/8 in the QKV-GEMM epilogue (cols < 1024).
// LESSONS: (R5) LDS row stride multiple of 8 ushorts for ds_read_b128.
// (R6/R8) DMA-staged LDS needs XOR source-swizzle. (R8/R9) dbuf DMA wins
// only with occupancy preserved (BK=32). (R11) per-wave global frags only
// at 1x redundancy. (R12) v9's 1-wave trips are DEPENDENCY-LATENCY bound:
// ~4.3k cyc/trip vs ~650 cyc of pipe work; chain = K ds_read -> S^T -> exp
// -> P roundtrip -> PV. R13 v10: software-pipeline across iterations —
// iter t runs S^T(t) (MFMA) concurrently with deferred exp/P/PV(t-1)
// (VALU+LDS); st crosses the boundary in registers.
// ---------------------------------------------------------------------------

typedef __attribute__((ext_vector_type(8))) short bf16x8;   // MFMA A/B frag
typedef __attribute__((ext_vector_type(4))) float f32x4;    // MFMA C/D frag
typedef __attribute__((ext_vector_type(4))) unsigned int u32x4;   // 16B copy
typedef __attribute__((ext_vector_type(4))) unsigned short u16x4; // 8B store
typedef __attribute__((ext_vector_type(8))) unsigned short u16x8; // 16B store

__device__ __forceinline__ unsigned short f2b(float f) {  // RNE f32->bf16
  unsigned int u = __float_as_uint(f);
  u = u + 0x7FFFu + ((u >> 16) & 1u);
  return (unsigned short)(u >> 16);
}
__device__ __forceinline__ unsigned short f2b_trunc(float f) {  // truncate
  return (unsigned short)(__float_as_uint(f) >> 16);
}

// async global->LDS DMA, 16B per lane; LDS dest = wave base + lane*16
__device__ __forceinline__ void gl_lds16(const unsigned short* g, unsigned short* s) {
  __builtin_amdgcn_global_load_lds((const __attribute__((address_space(1))) void*)g,
                                   (__attribute__((address_space(3))) void*)s, 16, 0, 0);
}

// ---------------- fp32 -> bf16, all three inputs in one launch -------------
__global__ __launch_bounds__(256) void cvt_all(const float* __restrict__ x,
                                               const float* __restrict__ wq,
                                               const float* __restrict__ wo,
                                               unsigned short* __restrict__ xb,
                                               unsigned short* __restrict__ wqb,
                                               unsigned short* __restrict__ wob) {
  const int bid = blockIdx.x;
  const float* in;
  unsigned short* out;
  int base;
  if (bid < 4096)      { in = x;  out = xb;  base = bid; }
  else if (bid < 7168) { in = wq; out = wqb; base = bid - 4096; }
  else                 { in = wo; out = wob; base = bid - 7168; }
  const int idx = (base * 256 + threadIdx.x) * 4;
  f32x4 v = *(const f32x4*)(in + idx);
  u16x4 r;
  r[0] = f2b(v[0]); r[1] = f2b(v[1]); r[2] = f2b(v[2]); r[3] = f2b(v[3]);
  *(u16x4*)(out + idx) = r;
}

// ---------------- GEMM: C[M,N] = (A[M,K] * W[N,K]^T + bias) * colscale -----
// 128x128 tile, BK=32, dbuf DMA (32KB LDS). Unchanged from R10.
__global__ __launch_bounds__(256) void gemm_bt(const unsigned short* __restrict__ A,
                                               const unsigned short* __restrict__ W,
                                               const float* __restrict__ bias,
                                               unsigned short* __restrict__ Cb,
                                               int M, int N, int K, int qcols) {
  __shared__ unsigned short As[2][128 * 32];
  __shared__ unsigned short Bs[2][128 * 32];
  const int tid  = threadIdx.x;
  const int lane = tid & 63;
  const int w    = tid >> 6;
  const int wy   = w >> 1, wx = w & 1;
  const int l15  = lane & 15, quad = lane >> 4;
  const int xr2  = (l15 >> 1) & 3;
  const int m0 = blockIdx.y * 128, n0 = blockIdx.x * 128;

  const unsigned short* gA[2];
  const unsigned short* gB[2];
  int off[2];
#pragma unroll
  for (int p = 0; p < 2; ++p) {
    const int c = tid + p * 256;
    const int r = c >> 2;
    const int srcc = (c & 3) ^ ((r >> 1) & 3);
    gA[p] = A + (size_t)(m0 + r) * K + srcc * 8;
    gB[p] = W + (size_t)(n0 + r) * K + srcc * 8;
    off[p] = c * 8;
  }

  f32x4 acc[4][4];
#pragma unroll
  for (int i = 0; i < 4; ++i)
#pragma unroll
    for (int j = 0; j < 4; ++j) acc[i][j] = (f32x4){0.f, 0.f, 0.f, 0.f};

#pragma unroll
  for (int p = 0; p < 2; ++p) {
    gl_lds16(gA[p], &As[0][off[p]]);
    gl_lds16(gB[p], &Bs[0][off[p]]);
  }

  const int NIT = K >> 5;
  for (int it = 0; it < NIT; ++it) {
    __syncthreads();
    const int cur = it & 1;
    if (it + 1 < NIT) {
      const int kt = (it + 1) << 5;
#pragma unroll
      for (int p = 0; p < 2; ++p) {
        gl_lds16(gA[p] + kt, &As[cur ^ 1][off[p]]);
        gl_lds16(gB[p] + kt, &Bs[cur ^ 1][off[p]]);
      }
    }
    const unsigned short* Ac = As[cur];
    const unsigned short* Bc = Bs[cur];
    bf16x8 af[4], bfr[4];
#pragma unroll
    for (int i = 0; i < 4; ++i)
      af[i] = *(const bf16x8*)&Ac[(wy * 64 + i * 16 + l15) * 32 + (quad ^ xr2) * 8];
#pragma unroll
    for (int j = 0; j < 4; ++j)
      bfr[j] = *(const bf16x8*)&Bc[(wx * 64 + j * 16 + l15) * 32 + (quad ^ xr2) * 8];
#pragma unroll
    for (int i = 0; i < 4; ++i)
#pragma unroll
      for (int j = 0; j < 4; ++j)
        acc[i][j] = __builtin_amdgcn_mfma_f32_16x16x32_bf16(af[i], bfr[j], acc[i][j], 0, 0, 0);
  }

#pragma unroll
  for (int i = 0; i < 4; ++i) {
    const int row = m0 + wy * 64 + i * 16 + quad * 4;
#pragma unroll
    for (int j = 0; j < 4; ++j) {
      const int col = n0 + wx * 64 + j * 16 + l15;
      const float bv = bias[col];
      const float sc = (col < qcols) ? 0.125f : 1.0f;
#pragma unroll
      for (int r = 0; r < 4; ++r)
        Cb[(size_t)(row + r) * N + col] = f2b((acc[i][j][r] + bv) * sc);
    }
  }
}

// ---------------- GEMM 64x64 tile, fp32 out (O-projection) -----------------
// Grid 16x64 = 1024 blocks, BK=32 dbuf, 16KB LDS. Unchanged from R11.
__global__ __launch_bounds__(256) void gemm_bt64(const unsigned short* __restrict__ A,
                                                 const unsigned short* __restrict__ W,
                                                 const float* __restrict__ bias,
                                                 float* __restrict__ Cf,
                                                 int M, int N, int K) {
  __shared__ unsigned short As[2][64 * 32];
  __shared__ unsigned short Bs[2][64 * 32];
  const int tid  = threadIdx.x;
  const int lane = tid & 63;
  const int w    = tid >> 6;
  const int wy   = w >> 1, wx = w & 1;
  const int l15  = lane & 15, quad = lane >> 4;
  const int xr2  = (l15 >> 1) & 3;
  const int m0 = blockIdx.y * 64, n0 = blockIdx.x * 64;

  const unsigned short* gA0;
  const unsigned short* gB0;
  int off0;
  {
    const int c = tid;
    const int r = c >> 2;
    const int srcc = (c & 3) ^ ((r >> 1) & 3);
    gA0 = A + (size_t)(m0 + r) * K + srcc * 8;
    gB0 = W + (size_t)(n0 + r) * K + srcc * 8;
    off0 = c * 8;
  }

  f32x4 acc[2][2];
#pragma unroll
  for (int i = 0; i < 2; ++i)
#pragma unroll
    for (int j = 0; j < 2; ++j) acc[i][j] = (f32x4){0.f, 0.f, 0.f, 0.f};

  gl_lds16(gA0, &As[0][off0]);
  gl_lds16(gB0, &Bs[0][off0]);

  const int NIT = K >> 5;
  for (int it = 0; it < NIT; ++it) {
    __syncthreads();
    const int cur = it & 1;
    if (it + 1 < NIT) {
      const int kt = (it + 1) << 5;
      gl_lds16(gA0 + kt, &As[cur ^ 1][off0]);
      gl_lds16(gB0 + kt, &Bs[cur ^ 1][off0]);
    }
    const unsigned short* Ac = As[cur];
    const unsigned short* Bc = Bs[cur];
    bf16x8 af[2], bfr[2];
#pragma unroll
    for (int i = 0; i < 2; ++i)
      af[i] = *(const bf16x8*)&Ac[(wy * 32 + i * 16 + l15) * 32 + (quad ^ xr2) * 8];
#pragma unroll
    for (int j = 0; j < 2; ++j)
      bfr[j] = *(const bf16x8*)&Bc[(wx * 32 + j * 16 + l15) * 32 + (quad ^ xr2) * 8];
#pragma unroll
    for (int i = 0; i < 2; ++i)
#pragma unroll
      for (int j = 0; j < 2; ++j)
        acc[i][j] = __builtin_amdgcn_mfma_f32_16x16x32_bf16(af[i], bfr[j], acc[i][j], 0, 0, 0);
  }

#pragma unroll
  for (int i = 0; i < 2; ++i) {
    const int row = m0 + wy * 32 + i * 16 + quad * 4;
#pragma unroll
    for (int j = 0; j < 2; ++j) {
      const int col = n0 + wx * 32 + j * 16 + l15;
      const float bv = bias[col];
#pragma unroll
      for (int r = 0; r < 4; ++r)
        Cf[(size_t)(row + r) * N + col] = acc[i][j][r] + bv;
    }
  }
}

// ---------------- V transpose: qkv V-part -> vt[(bh*64+d)][s] --------------
__global__ __launch_bounds__(256) void transpose_v(const unsigned short* __restrict__ qkv,
                                                   unsigned short* __restrict__ vt) {
  __shared__ unsigned short tile[64][72];
  const int tid = threadIdx.x;
  const int bh = blockIdx.y, b = bh >> 4, h = bh & 15;
  const int s0 = blockIdx.x * 64;
  const int i = tid >> 2;
  const int j = (tid & 3) * 16;
  const unsigned short* g = qkv + (size_t)(b * 2048 + s0 + i) * 3072 + 2048 + h * 64 + j;
  *(u32x4*)&tile[i][j]     = *(const u32x4*)g;
  *(u32x4*)&tile[i][j + 8] = *(const u32x4*)(g + 8);
  __syncthreads();
  const int d  = tid >> 2;
  const int sj = (tid & 3) * 16;
  u16x8 o0, o1;
#pragma unroll
  for (int k = 0; k < 8; ++k) { o0[k] = tile[sj + k][d]; o1[k] = tile[sj + 8 + k][d]; }
  unsigned short* gout = vt + (size_t)(bh * 64 + d) * 2048 + s0 + sj;
  *(u16x8*)gout       = o0;
  *(u16x8*)(gout + 8) = o1;
}

// ---------------- flash attention v10: cross-iter software pipeline --------
// 1-wave blocks, 32 q/wave, grid (bh 32, qt 64) = 2048 waves, LPT, XCD=bh%8.
// Iter t: [barrier: K DMA(t) drained] -> issue V loads for tile t-1 ->
// issue K DMA(t+1) -> ds_read K(t) -> S^T(t) MFMAs -> DEFERRED tile t-1:
// mask/exp (VALU, overlaps S^T on MFMA pipe per m114) -> P roundtrip -> PV.
// st crosses the iteration boundary in registers (st_old[2][4]).
// V loads issued before the DMA so PV's vmcnt wait excludes the DMA batch.
// LDS 18.9KB -> 8 blocks/CU. ~200 VGPR budgeted; launch_bounds(64,2).
__global__ __launch_bounds__(64, 2) void attn_fwd(const unsigned short* __restrict__ qkv,
                                                  const unsigned short* __restrict__ vt,
                                                  unsigned short* __restrict__ o) {
  __shared__ unsigned short Ks[2][64 * 64];  // packed DMA layout, XOR-swizzled
  __shared__ unsigned short P[16 * 72];
  const int lane = threadIdx.x;              // single wave
  const int l15 = lane & 15, quad = lane >> 4;
  const int xr = l15 & 7;
  const int bh = blockIdx.x, b = bh >> 4, h = bh & 15;
  const int qt = 63 - (int)blockIdx.y;       // LPT: heavy blocks first
  const int q0 = qt * 32;
  const int T = (qt >> 1) + 1;               // 64-kv tiles covering q0+31

  // K DMA source map: chunk c = p*64+lane: row=c>>3, col3=c&7,
  // swizzled source col = col3 ^ (row&7); LDS dest byte = c*16 (DMA-fixed).
  const unsigned short* gK[8];
#pragma unroll
  for (int p = 0; p < 8; ++p) {
    const int c = p * 64 + lane;
    const int r = c >> 3;
    const int sc = ((c & 7) ^ (r & 7)) * 8;
    gK[p] = qkv + (size_t)(b * 2048 + r) * 3072 + 1024 + h * 64 + sc;
  }

  // Q B-frags: 2 q-subtiles of 16; B[n=q(l15)][k=d(quad*8+j)]
  const unsigned short* qr0 = qkv + (size_t)(b * 2048 + q0 + l15) * 3072 + h * 64;
  const unsigned short* qr1 = qr0 + (size_t)16 * 3072;
  const bf16x8 bq[2][2] = {
    { *(const bf16x8*)(qr0 + quad * 8), *(const bf16x8*)(qr0 + 32 + quad * 8) },
    { *(const bf16x8*)(qr1 + quad * 8), *(const bf16x8*)(qr1 + 32 + quad * 8) } };

  const unsigned short* gV = vt + (size_t)(bh * 64) * 2048;

  bf16x8 vones;
#pragma unroll
  for (int k = 0; k < 8; ++k) vones[k] = (short)0x3F80;  // bf16 1.0

  f32x4 acc[2][4];   // O^T C-layout: col=q(l15), row=d(j*16+quad*4+r)
#pragma unroll
  for (int i = 0; i < 2; ++i)
#pragma unroll
    for (int j = 0; j < 4; ++j) acc[i][j] = (f32x4){0.f, 0.f, 0.f, 0.f};
  f32x4 accL[2] = {(f32x4){0.f, 0.f, 0.f, 0.f}, (f32x4){0.f, 0.f, 0.f, 0.f}};

  f32x4 st_old[2][4];  // deferred scores (tile t-1), live across iters

  // prologue: DMA K tile 0 -> buf 0
#pragma unroll
  for (int p = 0; p < 8; ++p) gl_lds16(gK[p], &Ks[0][p * 512]);

  for (int t = 0; t <= T; ++t) {
    __syncthreads();  // 1-wave: drains K DMA for buf(t&1)
    const int cur = t & 1;
    const bool have_cur = (t < T);
    const bool have_def = (t >= 1);
    const int kv0p = (t - 1) * 64;  // deferred tile's kv base

    // ---- V^T A-frags for DEFERRED tile (issued first: vmcnt ordering) ----
    bf16x8 av[4][2];
    if (have_def) {
#pragma unroll
      for (int j = 0; j < 4; ++j) {
        const unsigned short* vrow = gV + (size_t)(j * 16 + l15) * 2048 + kv0p;
        av[j][0] = *(const bf16x8*)(vrow + quad * 8);
        av[j][1] = *(const bf16x8*)(vrow + 32 + quad * 8);
      }
    }
    // ---- issue K(t+1) DMA into other buffer; drained at next barrier ----
    if (t + 1 < T) {
      const size_t ko = (size_t)(t + 1) * 64 * 3072;
#pragma unroll
      for (int p = 0; p < 8; ++p) gl_lds16(gK[p] + ko, &Ks[cur ^ 1][p * 512]);
    }
    // ---- S^T(t) = K Q^T (K frags from swizzled LDS) ----
    f32x4 stn[2][4];
    if (have_cur) {
      const unsigned short* Kc = Ks[cur];
      bf16x8 kA[4][2];
#pragma unroll
      for (int n = 0; n < 4; ++n) {
        const int row = n * 16 + l15;
        kA[n][0] = *(const bf16x8*)&Kc[row * 64 + ((quad) ^ xr) * 8];
        kA[n][1] = *(const bf16x8*)&Kc[row * 64 + ((4 + quad) ^ xr) * 8];
      }
#pragma unroll
      for (int qs = 0; qs < 2; ++qs)
#pragma unroll
        for (int n = 0; n < 4; ++n) {
          f32x4 z = (f32x4){0.f, 0.f, 0.f, 0.f};
          z = __builtin_amdgcn_mfma_f32_16x16x32_bf16(kA[n][0], bq[qs][0], z, 0, 0, 0);
          z = __builtin_amdgcn_mfma_f32_16x16x32_bf16(kA[n][1], bq[qs][1], z, 0, 0, 0);
          stn[qs][n] = z;
        }
    }
    // ---- DEFERRED tile t-1: mask/exp -> P roundtrip -> PV (overlaps S^T) --
    if (have_def) {
#pragma unroll
      for (int qs = 0; qs < 2; ++qs) {
        const int qbase = q0 + qs * 16;
        if (kv0p + 63 > qbase) {
          const int qrow = qbase + l15;
#pragma unroll
          for (int n = 0; n < 4; ++n)
#pragma unroll
            for (int r = 0; r < 4; ++r)
              if (kv0p + n * 16 + quad * 4 + r > qrow) st_old[qs][n][r] = -1e30f;
        }
#pragma unroll
        for (int n = 0; n < 4; ++n) {
#pragma unroll
          for (int r = 0; r < 4; ++r) st_old[qs][n][r] = __expf(st_old[qs][n][r]);
          u16x4 pw;
          pw[0] = f2b_trunc(st_old[qs][n][0]); pw[1] = f2b_trunc(st_old[qs][n][1]);
          pw[2] = f2b_trunc(st_old[qs][n][2]); pw[3] = f2b_trunc(st_old[qs][n][3]);
          *(u16x4*)&P[l15 * 72 + n * 16 + quad * 4] = pw;  // in-wave WAR safe
        }
        const bf16x8 bp0 = *(const bf16x8*)&P[l15 * 72 + quad * 8];
        const bf16x8 bp1 = *(const bf16x8*)&P[l15 * 72 + 32 + quad * 8];
        accL[qs] = __builtin_amdgcn_mfma_f32_16x16x32_bf16(vones, bp0, accL[qs], 0, 0, 0);
        accL[qs] = __builtin_amdgcn_mfma_f32_16x16x32_bf16(vones, bp1, accL[qs], 0, 0, 0);
#pragma unroll
        for (int j = 0; j < 4; ++j) {
          acc[qs][j] = __builtin_amdgcn_mfma_f32_16x16x32_bf16(av[j][0], bp0, acc[qs][j], 0, 0, 0);
          acc[qs][j] = __builtin_amdgcn_mfma_f32_16x16x32_bf16(av[j][1], bp1, acc[qs][j], 0, 0, 0);
        }
      }
    }
    // ---- rotate deferred state ----
    if (have_cur) {
#pragma unroll
      for (int qs = 0; qs < 2; ++qs)
#pragma unroll
        for (int n = 0; n < 4; ++n) st_old[qs][n] = stn[qs][n];
    }
  }
  // ---- epilogue: lane holds q=l15, d=j*16+quad*4+r -> packed u16x4 ----
#pragma unroll
  for (int qs = 0; qs < 2; ++qs) {
    const int qrow = q0 + qs * 16 + l15;
    const float inv = 1.0f / accL[qs][0];  // all rows of accL equal l[q]
    unsigned short* orow = o + (size_t)(b * 2048 + qrow) * 1024 + h * 64;
#pragma unroll
    for (int j = 0; j < 4; ++j) {
      u16x4 ov;
      ov[0] = f2b(acc[qs][j][0] * inv); ov[1] = f2b(acc[qs][j][1] * inv);
      ov[2] = f2b(acc[qs][j][2] * inv); ov[3] = f2b(acc[qs][j][3] * inv);
      *(u16x4*)(orow + j * 16 + quad * 4) = ov;
    }
  }
}

// ---------------------------------------------------------------------------
extern "C" void kernel_launch(void* const* d_in, const int* in_sizes, int n_in,
                              void* d_out, int out_size, void* d_ws, size_t ws_size,
                              hipStream_t stream) {
  const float* x       = (const float*)d_in[0];
  // d_in[1] = mask: causal tril by construction; implemented analytically.
  const float* w_qkv_w = (const float*)d_in[2];
  const float* w_qkv_b = (const float*)d_in[3];
  const float* w_o_w   = (const float*)d_in[4];
  const float* w_o_b   = (const float*)d_in[5];
  float* out = (float*)d_out;

  unsigned short* ws    = (unsigned short*)d_ws;
  unsigned short* xb    = ws;                                  // 4096*1024
  unsigned short* wqb   = xb   + (size_t)4096 * 1024;          // 3072*1024
  unsigned short* wob   = wqb  + (size_t)3072 * 1024;          // 1024*1024
  unsigned short* qkvb  = wob  + (size_t)1024 * 1024;          // 4096*3072
  unsigned short* vtb   = qkvb + (size_t)4096 * 3072;          // 2048*2048
  unsigned short* attnb = vtb  + (size_t)2048 * 2048;          // 4096*1024

  cvt_all<<<8192, 256, 0, stream>>>(x, w_qkv_w, w_o_w, xb, wqb, wob);
  gemm_bt<<<dim3(24, 32), 256, 0, stream>>>(xb, wqb, w_qkv_b, qkvb, 4096, 3072, 1024, 1024);
  transpose_v<<<dim3(32, 32), 256, 0, stream>>>(qkvb, vtb);
  attn_fwd<<<dim3(32, 64), 64, 0, stream>>>(qkvb, vtb, attnb);
  gemm_bt64<<<dim3(16, 64), 256, 0, stream>>>(attnb, wob, w_o_b, out, 4096, 1024, 1024);
}

// Round 14
// 190.772 us; speedup vs baseline: 1.0726x; 1.0726x over previous
//
#include <hip/hip_runtime.h>
#include <cstdint>
#include <cstddef>

// ---------------------------------------------------------------------------
// ChatGPTAttention: x[2,2048,1024] -> QKV proj -> causal MHA (16 heads, dk=64)
//                   -> O proj. bf16 MFMA pipeline, fp32 accumulate.
// Q is pre-scaled by 1/8 in the QKV-GEMM epilogue (cols < 1024).
// LESSONS: (R5) LDS row stride multiple of 8 ushorts for ds_read_b128.
// (R6/R8) DMA-staged LDS needs XOR source-swizzle. (R8/R9) dbuf DMA wins
// only with occupancy preserved (BK=32). (R11) per-wave global frags only at
// 1x redundancy. (R12/R13) 1-wave attn is dependency-latency bound (~4.3k
// cyc/trip vs 650 cyc pipe work); register pipelining didn't decouple the
// shared lgkm/vmcnt waits -> reverted to v7 (4-wave, 46us known-good).
// (R9-R13) totals pinned ~196-205 while attn swung 46-85: non-attn remainder
// ~150us, each kernel <46 -> ~10us/launch serialization gaps suspected.
// R14: kill one launch — transpose_v fused into gemm_bt epilogue (V-column
// blocks store u16x4 directly into vt; qkvb V-region never written/read).
// ---------------------------------------------------------------------------

typedef __attribute__((ext_vector_type(8))) short bf16x8;   // MFMA A/B frag
typedef __attribute__((ext_vector_type(4))) float f32x4;    // MFMA C/D frag
typedef __attribute__((ext_vector_type(4))) unsigned int u32x4;   // 16B copy
typedef __attribute__((ext_vector_type(4))) unsigned short u16x4; // 8B store
typedef __attribute__((ext_vector_type(8))) unsigned short u16x8; // 16B store

__device__ __forceinline__ unsigned short f2b(float f) {  // RNE f32->bf16
  unsigned int u = __float_as_uint(f);
  u = u + 0x7FFFu + ((u >> 16) & 1u);
  return (unsigned short)(u >> 16);
}
__device__ __forceinline__ unsigned short f2b_trunc(float f) {  // truncate
  return (unsigned short)(__float_as_uint(f) >> 16);
}

// async global->LDS DMA, 16B per lane; LDS dest = wave base + lane*16
__device__ __forceinline__ void gl_lds16(const unsigned short* g, unsigned short* s) {
  __builtin_amdgcn_global_load_lds((const __attribute__((address_space(1))) void*)g,
                                   (__attribute__((address_space(3))) void*)s, 16, 0, 0);
}

// ---------------- fp32 -> bf16, all three inputs in one launch -------------
__global__ __launch_bounds__(256) void cvt_all(const float* __restrict__ x,
                                               const float* __restrict__ wq,
                                               const float* __restrict__ wo,
                                               unsigned short* __restrict__ xb,
                                               unsigned short* __restrict__ wqb,
                                               unsigned short* __restrict__ wob) {
  const int bid = blockIdx.x;
  const float* in;
  unsigned short* out;
  int base;
  if (bid < 4096)      { in = x;  out = xb;  base = bid; }
  else if (bid < 7168) { in = wq; out = wqb; base = bid - 4096; }
  else                 { in = wo; out = wob; base = bid - 7168; }
  const int idx = (base * 256 + threadIdx.x) * 4;
  f32x4 v = *(const f32x4*)(in + idx);
  u16x4 r;
  r[0] = f2b(v[0]); r[1] = f2b(v[1]); r[2] = f2b(v[2]); r[3] = f2b(v[3]);
  *(u16x4*)(out + idx) = r;
}

// ---------------- GEMM: C[M,N] = (A[M,K] * W[N,K]^T + bias) * colscale -----
// 128x128 tile, BK=32, dbuf DMA (32KB LDS). R14: V-column blocks (n0>=2048,
// block-uniform) write their output TRANSPOSED into vt[(bh*64+d)*2048+s] as
// packed u16x4 (C/D layout: lane's 4 regs = 4 consecutive s) — transpose_v
// kernel eliminated; qkvb V-region never touched.
__global__ __launch_bounds__(256) void gemm_bt(const unsigned short* __restrict__ A,
                                               const unsigned short* __restrict__ W,
                                               const float* __restrict__ bias,
                                               unsigned short* __restrict__ Cb,
                                               unsigned short* __restrict__ vtb,
                                               int M, int N, int K, int qcols) {
  __shared__ unsigned short As[2][128 * 32];
  __shared__ unsigned short Bs[2][128 * 32];
  const int tid  = threadIdx.x;
  const int lane = tid & 63;
  const int w    = tid >> 6;
  const int wy   = w >> 1, wx = w & 1;
  const int l15  = lane & 15, quad = lane >> 4;
  const int xr2  = (l15 >> 1) & 3;
  const int m0 = blockIdx.y * 128, n0 = blockIdx.x * 128;

  const unsigned short* gA[2];
  const unsigned short* gB[2];
  int off[2];
#pragma unroll
  for (int p = 0; p < 2; ++p) {
    const int c = tid + p * 256;
    const int r = c >> 2;
    const int srcc = (c & 3) ^ ((r >> 1) & 3);
    gA[p] = A + (size_t)(m0 + r) * K + srcc * 8;
    gB[p] = W + (size_t)(n0 + r) * K + srcc * 8;
    off[p] = c * 8;
  }

  f32x4 acc[4][4];
#pragma unroll
  for (int i = 0; i < 4; ++i)
#pragma unroll
    for (int j = 0; j < 4; ++j) acc[i][j] = (f32x4){0.f, 0.f, 0.f, 0.f};

#pragma unroll
  for (int p = 0; p < 2; ++p) {
    gl_lds16(gA[p], &As[0][off[p]]);
    gl_lds16(gB[p], &Bs[0][off[p]]);
  }

  const int NIT = K >> 5;
  for (int it = 0; it < NIT; ++it) {
    __syncthreads();
    const int cur = it & 1;
    if (it + 1 < NIT) {
      const int kt = (it + 1) << 5;
#pragma unroll
      for (int p = 0; p < 2; ++p) {
        gl_lds16(gA[p] + kt, &As[cur ^ 1][off[p]]);
        gl_lds16(gB[p] + kt, &Bs[cur ^ 1][off[p]]);
      }
    }
    const unsigned short* Ac = As[cur];
    const unsigned short* Bc = Bs[cur];
    bf16x8 af[4], bfr[4];
#pragma unroll
    for (int i = 0; i < 4; ++i)
      af[i] = *(const bf16x8*)&Ac[(wy * 64 + i * 16 + l15) * 32 + (quad ^ xr2) * 8];
#pragma unroll
    for (int j = 0; j < 4; ++j)
      bfr[j] = *(const bf16x8*)&Bc[(wx * 64 + j * 16 + l15) * 32 + (quad ^ xr2) * 8];
#pragma unroll
    for (int i = 0; i < 4; ++i)
#pragma unroll
      for (int j = 0; j < 4; ++j)
        acc[i][j] = __builtin_amdgcn_mfma_f32_16x16x32_bf16(af[i], bfr[j], acc[i][j], 0, 0, 0);
  }

  const bool vblock = (n0 >= 2048);  // block-uniform: tile cols all >= 2048
#pragma unroll
  for (int i = 0; i < 4; ++i) {
    const int row = m0 + wy * 64 + i * 16 + quad * 4;
#pragma unroll
    for (int j = 0; j < 4; ++j) {
      const int col = n0 + wx * 64 + j * 16 + l15;
      const float bv = bias[col];
      if (!vblock) {
        const float sc = (col < qcols) ? 0.125f : 1.0f;
#pragma unroll
        for (int r = 0; r < 4; ++r)
          Cb[(size_t)(row + r) * N + col] = f2b((acc[i][j][r] + bv) * sc);
      } else {
        // V-part: write V^T. row = b*2048+s (4-aligned, same b for all r);
        // vt index (b*1024 + (col-2048)) * 2048 + s, 4 consecutive s.
        const int hd = col - 2048;
        const int bb = row >> 11, s = row & 2047;
        u16x4 ov;
#pragma unroll
        for (int r = 0; r < 4; ++r) ov[r] = f2b(acc[i][j][r] + bv);
        *(u16x4*)(vtb + ((size_t)(bb * 1024 + hd)) * 2048 + s) = ov;
      }
    }
  }
}

// ---------------- GEMM 64x64 tile, fp32 out (O-projection) -----------------
// Grid 16x64 = 1024 blocks, BK=32 dbuf, 16KB LDS. Unchanged from R11.
__global__ __launch_bounds__(256) void gemm_bt64(const unsigned short* __restrict__ A,
                                                 const unsigned short* __restrict__ W,
                                                 const float* __restrict__ bias,
                                                 float* __restrict__ Cf,
                                                 int M, int N, int K) {
  __shared__ unsigned short As[2][64 * 32];
  __shared__ unsigned short Bs[2][64 * 32];
  const int tid  = threadIdx.x;
  const int lane = tid & 63;
  const int w    = tid >> 6;
  const int wy   = w >> 1, wx = w & 1;
  const int l15  = lane & 15, quad = lane >> 4;
  const int xr2  = (l15 >> 1) & 3;
  const int m0 = blockIdx.y * 64, n0 = blockIdx.x * 64;

  const unsigned short* gA0;
  const unsigned short* gB0;
  int off0;
  {
    const int c = tid;
    const int r = c >> 2;
    const int srcc = (c & 3) ^ ((r >> 1) & 3);
    gA0 = A + (size_t)(m0 + r) * K + srcc * 8;
    gB0 = W + (size_t)(n0 + r) * K + srcc * 8;
    off0 = c * 8;
  }

  f32x4 acc[2][2];
#pragma unroll
  for (int i = 0; i < 2; ++i)
#pragma unroll
    for (int j = 0; j < 2; ++j) acc[i][j] = (f32x4){0.f, 0.f, 0.f, 0.f};

  gl_lds16(gA0, &As[0][off0]);
  gl_lds16(gB0, &Bs[0][off0]);

  const int NIT = K >> 5;
  for (int it = 0; it < NIT; ++it) {
    __syncthreads();
    const int cur = it & 1;
    if (it + 1 < NIT) {
      const int kt = (it + 1) << 5;
      gl_lds16(gA0 + kt, &As[cur ^ 1][off0]);
      gl_lds16(gB0 + kt, &Bs[cur ^ 1][off0]);
    }
    const unsigned short* Ac = As[cur];
    const unsigned short* Bc = Bs[cur];
    bf16x8 af[2], bfr[2];
#pragma unroll
    for (int i = 0; i < 2; ++i)
      af[i] = *(const bf16x8*)&Ac[(wy * 32 + i * 16 + l15) * 32 + (quad ^ xr2) * 8];
#pragma unroll
    for (int j = 0; j < 2; ++j)
      bfr[j] = *(const bf16x8*)&Bc[(wx * 32 + j * 16 + l15) * 32 + (quad ^ xr2) * 8];
#pragma unroll
    for (int i = 0; i < 2; ++i)
#pragma unroll
      for (int j = 0; j < 2; ++j)
        acc[i][j] = __builtin_amdgcn_mfma_f32_16x16x32_bf16(af[i], bfr[j], acc[i][j], 0, 0, 0);
  }

#pragma unroll
  for (int i = 0; i < 2; ++i) {
    const int row = m0 + wy * 32 + i * 16 + quad * 4;
#pragma unroll
    for (int j = 0; j < 2; ++j) {
      const int col = n0 + wx * 32 + j * 16 + l15;
      const float bv = bias[col];
#pragma unroll
      for (int r = 0; r < 4; ++r)
        Cf[(size_t)(row + r) * N + col] = acc[i][j][r] + bv;
    }
  }
}

// ---------------- flash attention v7 (R9/R10 known-good: 46.2us) -----------
// 4 waves, 32 q/wave, S^T=KQ^T, O^T=V^T P^T, shared 16x72 P buffer per wave
// (in-wave DS ordering), LDS 45KB -> 3 blocks/CU. Grid (bh 32, qt 16), LPT.
__global__ __launch_bounds__(256, 3) void attn_fwd(const unsigned short* __restrict__ qkv,
                                                   const unsigned short* __restrict__ vt,
                                                   unsigned short* __restrict__ o) {
  __shared__ unsigned short Ks[2][64 * 72];
  __shared__ unsigned short Vs[2][64 * 72];
  __shared__ unsigned short pbuf[4][16 * 72];
  const int tid  = threadIdx.x;
  const int lane = tid & 63;
  const int w    = tid >> 6;
  const int l15  = lane & 15, quad = lane >> 4;
  const int bh = blockIdx.x, b = bh >> 4, h = bh & 15;
  const int qt = 15 - (int)blockIdx.y;  // LPT order
  const int q0 = qt * 128;
  const int qa = q0 + w * 32;
  const int qb = qa + 16;
  const int T = 2 * qt + 2;

  const int srow = tid >> 2;
  const int scol = (tid & 3) * 16;
  const unsigned short* gK = qkv + (size_t)(b * 2048 + srow) * 3072 + 1024 + h * 64 + scol;
  const unsigned short* gV = vt + (size_t)(bh * 64 + srow) * 2048 + scol;

  const unsigned short* qra = qkv + (size_t)(b * 2048 + qa + l15) * 3072 + h * 64;
  const unsigned short* qrb = qkv + (size_t)(b * 2048 + qb + l15) * 3072 + h * 64;
  const bf16x8 bq[2][2] = {
    { *(const bf16x8*)(qra + quad * 8), *(const bf16x8*)(qra + 32 + quad * 8) },
    { *(const bf16x8*)(qrb + quad * 8), *(const bf16x8*)(qrb + 32 + quad * 8) } };

  bf16x8 vones;
#pragma unroll
  for (int k = 0; k < 8; ++k) vones[k] = (short)0x3F80;  // bf16 1.0

  f32x4 acc[2][4];   // [q-tile][d-tile] — O^T C-layout: col=q(l15), row=d
#pragma unroll
  for (int i = 0; i < 2; ++i)
#pragma unroll
    for (int j = 0; j < 4; ++j) acc[i][j] = (f32x4){0.f, 0.f, 0.f, 0.f};
  f32x4 accL[2] = {(f32x4){0.f, 0.f, 0.f, 0.f}, (f32x4){0.f, 0.f, 0.f, 0.f}};

  unsigned short* P = pbuf[w];  // [q 0..15][kv 0..63], stride 72

  {  // prologue: stage trip 0 into buf 0
    u32x4 k0 = *(const u32x4*)gK, k1 = *(const u32x4*)(gK + 8);
    u32x4 v0 = *(const u32x4*)gV, v1 = *(const u32x4*)(gV + 8);
    unsigned short* sK = &Ks[0][srow * 72 + scol];
    unsigned short* sV = &Vs[0][srow * 72 + scol];
    *(u32x4*)sK = k0; *(u32x4*)(sK + 8) = k1;
    *(u32x4*)sV = v0; *(u32x4*)(sV + 8) = v1;
  }

  for (int t = 0; t < T; ++t) {
    __syncthreads();  // buf(t&1) staged; WAR-protects other buf rewrite
    const int cur = t & 1;
    const unsigned short* Kc = Ks[cur];
    const unsigned short* Vc = Vs[cur];
    u32x4 nk0, nk1, nv0, nv1;
    const bool more = (t + 1 < T);
    if (more) {
      const size_t ko = (size_t)(t + 1) * 64 * 3072;
      const int vo = (t + 1) * 64;
      nk0 = *(const u32x4*)(gK + ko); nk1 = *(const u32x4*)(gK + ko + 8);
      nv0 = *(const u32x4*)(gV + vo); nv1 = *(const u32x4*)(gV + vo + 8);
    }
    const int kv0 = t * 64;

    f32x4 st[2][4];
#pragma unroll
    for (int n = 0; n < 4; ++n) {
      const bf16x8 kA0 = *(const bf16x8*)&Kc[(n * 16 + l15) * 72 + quad * 8];
      const bf16x8 kA1 = *(const bf16x8*)&Kc[(n * 16 + l15) * 72 + 32 + quad * 8];
      f32x4 z0 = (f32x4){0.f, 0.f, 0.f, 0.f};
      z0 = __builtin_amdgcn_mfma_f32_16x16x32_bf16(kA0, bq[0][0], z0, 0, 0, 0);
      z0 = __builtin_amdgcn_mfma_f32_16x16x32_bf16(kA1, bq[0][1], z0, 0, 0, 0);
      st[0][n] = z0;
      f32x4 z1 = (f32x4){0.f, 0.f, 0.f, 0.f};
      z1 = __builtin_amdgcn_mfma_f32_16x16x32_bf16(kA0, bq[1][0], z1, 0, 0, 0);
      z1 = __builtin_amdgcn_mfma_f32_16x16x32_bf16(kA1, bq[1][1], z1, 0, 0, 0);
      st[1][n] = z1;
    }
    bf16x8 av[4][2];
#pragma unroll
    for (int j = 0; j < 4; ++j) {
      av[j][0] = *(const bf16x8*)&Vc[(j * 16 + l15) * 72 + quad * 8];
      av[j][1] = *(const bf16x8*)&Vc[(j * 16 + l15) * 72 + 32 + quad * 8];
    }
#pragma unroll
    for (int tq = 0; tq < 2; ++tq) {
      const int qbase = tq ? qb : qa;
      if (kv0 + 63 > qbase) {
        const int qrow = qbase + l15;
#pragma unroll
        for (int n = 0; n < 4; ++n)
#pragma unroll
          for (int r = 0; r < 4; ++r)
            if (kv0 + n * 16 + quad * 4 + r > qrow) st[tq][n][r] = -1e30f;
      }
#pragma unroll
      for (int n = 0; n < 4; ++n) {
#pragma unroll
        for (int r = 0; r < 4; ++r) st[tq][n][r] = __expf(st[tq][n][r]);
        u16x4 pw;
        pw[0] = f2b_trunc(st[tq][n][0]); pw[1] = f2b_trunc(st[tq][n][1]);
        pw[2] = f2b_trunc(st[tq][n][2]); pw[3] = f2b_trunc(st[tq][n][3]);
        *(u16x4*)&P[l15 * 72 + n * 16 + quad * 4] = pw;  // in-wave WAR safe
      }
      const bf16x8 bp0 = *(const bf16x8*)&P[l15 * 72 + quad * 8];
      const bf16x8 bp1 = *(const bf16x8*)&P[l15 * 72 + 32 + quad * 8];
      accL[tq] = __builtin_amdgcn_mfma_f32_16x16x32_bf16(vones, bp0, accL[tq], 0, 0, 0);
      accL[tq] = __builtin_amdgcn_mfma_f32_16x16x32_bf16(vones, bp1, accL[tq], 0, 0, 0);
#pragma unroll
      for (int j = 0; j < 4; ++j) {
        acc[tq][j] = __builtin_amdgcn_mfma_f32_16x16x32_bf16(av[j][0], bp0, acc[tq][j], 0, 0, 0);
        acc[tq][j] = __builtin_amdgcn_mfma_f32_16x16x32_bf16(av[j][1], bp1, acc[tq][j], 0, 0, 0);
      }
    }
    if (more) {
      unsigned short* sK = &Ks[cur ^ 1][srow * 72 + scol];
      unsigned short* sV = &Vs[cur ^ 1][srow * 72 + scol];
      *(u32x4*)sK = nk0; *(u32x4*)(sK + 8) = nk1;
      *(u32x4*)sV = nv0; *(u32x4*)(sV + 8) = nv1;
    }
  }
#pragma unroll
  for (int tq = 0; tq < 2; ++tq) {
    const int qrow = (tq ? qb : qa) + l15;
    const float inv = 1.0f / accL[tq][0];  // all rows of accL equal l[q]
    unsigned short* orow = o + (size_t)(b * 2048 + qrow) * 1024 + h * 64;
#pragma unroll
    for (int j = 0; j < 4; ++j) {
      u16x4 ov;
      ov[0] = f2b(acc[tq][j][0] * inv); ov[1] = f2b(acc[tq][j][1] * inv);
      ov[2] = f2b(acc[tq][j][2] * inv); ov[3] = f2b(acc[tq][j][3] * inv);
      *(u16x4*)(orow + j * 16 + quad * 4) = ov;
    }
  }
}

// ---------------------------------------------------------------------------
extern "C" void kernel_launch(void* const* d_in, const int* in_sizes, int n_in,
                              void* d_out, int out_size, void* d_ws, size_t ws_size,
                              hipStream_t stream) {
  const float* x       = (const float*)d_in[0];
  // d_in[1] = mask: causal tril by construction; implemented analytically.
  const float* w_qkv_w = (const float*)d_in[2];
  const float* w_qkv_b = (const float*)d_in[3];
  const float* w_o_w   = (const float*)d_in[4];
  const float* w_o_b   = (const float*)d_in[5];
  float* out = (float*)d_out;

  unsigned short* ws    = (unsigned short*)d_ws;
  unsigned short* xb    = ws;                                  // 4096*1024
  unsigned short* wqb   = xb   + (size_t)4096 * 1024;          // 3072*1024
  unsigned short* wob   = wqb  + (size_t)3072 * 1024;          // 1024*1024
  unsigned short* qkvb  = wob  + (size_t)1024 * 1024;          // 4096*3072
  unsigned short* vtb   = qkvb + (size_t)4096 * 3072;          // 2048*2048
  unsigned short* attnb = vtb  + (size_t)2048 * 2048;          // 4096*1024

  cvt_all<<<8192, 256, 0, stream>>>(x, w_qkv_w, w_o_w, xb, wqb, wob);
  gemm_bt<<<dim3(24, 32), 256, 0, stream>>>(xb, wqb, w_qkv_b, qkvb, vtb, 4096, 3072, 1024, 1024);
  attn_fwd<<<dim3(32, 16), 256, 0, stream>>>(qkvb, vtb, attnb);
  gemm_bt64<<<dim3(16, 64), 256, 0, stream>>>(attnb, wob, w_o_b, out, 4096, 1024, 1024);
}